// Round 14
// baseline (734.165 us; speedup 1.0000x reference)
//
#include <hip/hip_runtime.h>
#include <stdint.h>

// out[8192,4096] = x @ (Wd + Ws)^T, fp32 device buffers (harness upcasts fp16).
// Wd,Ws elementwise complementary -> W = Wd+Ws exact, fp16-representable.
// Path A (ws >= 96MB): fused cvt -> bf16 in ws, then 256^2 MFMA GEMM where
//   A-fragments load DIRECTLY from global (vector pipe, L1/L2-served) and only
//   B goes through LDS (halves LDS traffic; r13 proved LDS+MFMA serialize
//   while the vector pipe overlaps). B staging/swizzle/epilogue = r12-verified.
// Path B: round-3-verified fused reg-staged GEMM (fallback, f16).

#define NT 8192
#define NO 4096
#define NK 4096

typedef float f32x4 __attribute__((ext_vector_type(4)));
typedef _Float16 f16x8 __attribute__((ext_vector_type(8)));
typedef __bf16 bf16x8 __attribute__((ext_vector_type(8)));
typedef short short8 __attribute__((ext_vector_type(8)));

__device__ __forceinline__ void gload_lds16(const void* g, void* l) {
  __builtin_amdgcn_global_load_lds(
      (const __attribute__((address_space(1))) void*)g,
      (__attribute__((address_space(3))) void*)l, 16, 0, 0);
}

#define BAR() __builtin_amdgcn_s_barrier()
#define WV28() asm volatile("s_waitcnt vmcnt(28)" ::: "memory")
#define WV12() asm volatile("s_waitcnt vmcnt(12)" ::: "memory")
#define WV0() asm volatile("s_waitcnt vmcnt(0)" ::: "memory")
#define PRIO1() __builtin_amdgcn_s_setprio(1)
#define PRIO0() __builtin_amdgcn_s_setprio(0)

__device__ __forceinline__ short f32_bf16(float f) {
  uint32_t u = __float_as_uint(f);
  u += 0x7FFFu + ((u >> 16) & 1u);  // RNE
  return (short)(u >> 16);
}

// ---- pre-pass: fp32 -> bf16, x and W=Wd+Ws in one launch ----
__global__ __launch_bounds__(256) void cvt_all(
    const float* __restrict__ x, const float* __restrict__ wd,
    const float* __restrict__ ws, short* __restrict__ xh,
    short* __restrict__ wh, int nx8, int nw8) {
  int i = blockIdx.x * 256 + threadIdx.x;
  if (i < nx8) {
    const f32x4* p = (const f32x4*)x + 2 * (size_t)i;
    f32x4 lo = p[0], hi = p[1];
    short8 r;
#pragma unroll
    for (int j = 0; j < 4; ++j) { r[j] = f32_bf16(lo[j]); r[j + 4] = f32_bf16(hi[j]); }
    *((short8*)xh + i) = r;
  } else {
    int j8 = i - nx8;
    if (j8 < nw8) {
      const f32x4* pd = (const f32x4*)wd + 2 * (size_t)j8;
      const f32x4* ps = (const f32x4*)ws + 2 * (size_t)j8;
      f32x4 dl = pd[0], dh = pd[1], sl = ps[0], sh = ps[1];
      short8 r;
#pragma unroll
      for (int j = 0; j < 4; ++j) {
        r[j] = f32_bf16(dl[j] + sl[j]);      // add exact: one addend is +/-0
        r[j + 4] = f32_bf16(dh[j] + sh[j]);
      }
      *((short8*)wh + j8) = r;
    }
  }
}

// ---- 256^2 GEMM: A from global->regs, B via LDS (64KB, st_16x32) ----
// 8 waves (2Mx4N), per-wave out 128x64. LDS [buf][half][8192 shorts] = 64KB.
// A-frag (lane): row = brow + wr*128 + MG*64 + mm*16 + fr, k = kt + ks*32 + kq*8
//   -> 16B contiguous per lane; slice is L1/L2-resident (4x wave reuse).
// B staging: linear global_load_lds dest + inverse-swizzled source (verified).

#define GLA(MG_, KT_) do { _Pragma("unroll") \
  for (int mm = 0; mm < 4; ++mm) { \
    ar[0][mm] = *(const short8*)(Arow + ((MG_)*64 + mm*16) * (long)NK + (KT_)); \
    ar[1][mm] = *(const short8*)(Arow + ((MG_)*64 + mm*16) * (long)NK + (KT_) + 32); \
  } } while (0)

#define LDB(B_, NG) do { _Pragma("unroll") \
  for (int nn = 0; nn < 2; ++nn) { \
    br[0][(NG)*2+nn] = *(const short8*)(Bb[B_] + ((bsub + (NG)*2 + nn)*2 + 0) * 1024 + finner); \
    br[1][(NG)*2+nn] = *(const short8*)(Bb[B_] + ((bsub + (NG)*2 + nn)*2 + 1) * 1024 + finner); \
  } } while (0)

// swapped operands: D-row dim = W(N), D-col dim = X(M) -> contiguous-N acc
#define MM(MG, NG) do { PRIO1(); _Pragma("unroll") \
  for (int ks = 0; ks < 2; ++ks) \
    _Pragma("unroll") for (int mm = 0; mm < 4; ++mm) \
      _Pragma("unroll") for (int nn = 0; nn < 2; ++nn) \
        acc[(MG)*4+mm][(NG)*2+nn] = __builtin_amdgcn_mfma_f32_16x16x32_bf16( \
            __builtin_bit_cast(bf16x8, br[ks][(NG)*2+nn]), \
            __builtin_bit_cast(bf16x8, ar[ks][mm]), \
            acc[(MG)*4+mm][(NG)*2+nn], 0, 0, 0); \
  PRIO0(); } while (0)

#define STGB(BUF_, H_, S_, KCOL) \
  gload_lds16(Wrow + ((H_)*128 + (S_)*64) * NK + (KCOL), \
              ldsc + (BUF_)*32768 + (H_)*16384 + (S_)*8192 + t16)

__global__ __launch_bounds__(512, 2) void gemm8p(
    const short* __restrict__ Xg, const short* __restrict__ Wg,
    float* __restrict__ C) {
  __shared__ short lds[2][2][8192];  // [buf][half][16KB] = 64 KiB (B only)
  char* ldsc = (char*)&lds[0][0][0];

  const int t = threadIdx.x;      // 0..511
  const int lane = t & 63;
  const int wv = t >> 6;          // 0..7
  const int wr = wv >> 2;         // 0..1  (M half)
  const int wc = wv & 3;          // 0..3  (N quarter)
  const int fr = lane & 15;
  const int kq = lane >> 4;       // 0..3
  const int t16 = t * 16;

  // XCD-aware bijective swizzle (nwg = 512 = 8*64)
  const int swz = (blockIdx.x & 7) * 64 + (blockIdx.x >> 3);
  const int bm = swz >> 4, bn = swz & 15;   // 32 x 16 tiles
  const int brow = bm * 256, bcol = bn * 256;

  // B staging: invert st_16x32 swizzle on the global source (verified r5-r12)
  const int o = t16;
  const int sub = o >> 10;
  const int inner = o & 1023;
  const int innsw = inner ^ (((inner >> 9) & 1) << 5);
  const int rloc = ((sub >> 1) << 4) | ((innsw >> 6) & 15);  // 0..63
  const int kloc = ((sub & 1) << 5) | ((innsw >> 1) & 31);   // 0..63 (8-granular)
  const short* Wrow = Wg + (bcol + rloc) * NK + kloc;

  // A direct-from-global base
  const short* Arow = Xg + (brow + wr * 128 + fr) * (long)NK + kq * 8;

  // B fragment read constants (same verified 0-conflict pattern)
  const int finner = ((fr << 6) | (kq << 4)) ^ ((fr & 8) << 2);
  const char* Bb[2] = { ldsc + (wc >> 1) * 16384,
                        ldsc + 32768 + (wc >> 1) * 16384 };
  const int bsub = (wc & 1) * 4;

  short8 ar[2][4], br[2][4];
  f32x4 acc[8][4] = {};

  // ---- prologue: B tile0 -> buf0, B tile1 -> buf1; A(tile0, MG0) ----
  STGB(0, 0, 0, 0); STGB(0, 0, 1, 0); STGB(0, 1, 0, 0); STGB(0, 1, 1, 0);
  STGB(1, 0, 0, 64); STGB(1, 0, 1, 64); STGB(1, 1, 0, 64); STGB(1, 1, 1, 64);
  GLA(0, 0);
  WV12(); BAR();   // buf0.B (4 oldest of 12 in flight) complete

#pragma unroll 1
  for (int i = 0; i < NK / 128 - 1; ++i) {   // i = 0..30; last iter peeled
    const int kc = i * 128;
    const int kt2 = kc + 128;  // tile 2i+2 (valid: last iter peeled)
    const int kt3 = kc + 192;  // tile 2i+3

    // P0: B n0-1 from buf0; MFMA(m0-3 x n0-1)
    LDB(0, 0);
    MM(0, 0); BAR();
    // P1: B n2-3; MFMA(m0-3 x n2-3); then A(MG1, tile2i) for P2 (WAR-ordered)
    LDB(0, 1);
    MM(0, 1);
    GLA(1, kc);
    BAR();
    // P2: stage B(t+2) half0 -> buf0; MFMA(m4-7 x n0-1)
    STGB(0, 0, 0, kt2); STGB(0, 0, 1, kt2);
    MM(1, 0); BAR();
    // P3: stage B(t+2) half1; MFMA(m4-7 x n2-3); A(MG0, tile2i+1) for P4
    STGB(0, 1, 0, kt2); STGB(0, 1, 1, kt2);
    MM(1, 1);
    GLA(0, kc + 64);
    WV28(); BAR();   // prev-iter buf1.B stages (older than newest 28) done
    // P4..P7: mirror on buf1 (tile 2i+1), stage tile 2i+3
    LDB(1, 0);
    MM(0, 0); BAR();
    LDB(1, 1);
    MM(0, 1);
    GLA(1, kc + 64);
    BAR();
    STGB(1, 0, 0, kt3); STGB(1, 0, 1, kt3);
    MM(1, 0); BAR();
    STGB(1, 1, 0, kt3); STGB(1, 1, 1, kt3);
    MM(1, 1);
    GLA(0, kt2);     // A(MG0, tile 2i+2) for next P0
    WV28(); BAR();   // this-iter buf0.B stages done before next P0
  }

  // ---- peeled final iteration (tiles 62 @buf0, 63 @buf1): no staging ----
  {
    const int kc = (NK / 128 - 1) * 128;  // 3968
    LDB(0, 0); MM(0, 0); BAR();
    LDB(0, 1); MM(0, 1); GLA(1, kc); BAR();
    MM(1, 0); BAR();
    MM(1, 1); GLA(0, kc + 64);
    WV0(); BAR();    // drain everything before buf1 reads
    LDB(1, 0); MM(0, 0); BAR();
    LDB(1, 1); MM(0, 1); GLA(1, kc + 64); BAR();
    MM(1, 0); BAR();
    MM(1, 1);
  }

  // Swapped-operand C/D layout: lane's 4 acc elems are CONTIGUOUS in N.
  // row = brow + wr*128 + m*16 + fr ; col = bcol + wc*64 + n*16 + kq*4 + [0,4)
  const long r0 = brow + wr * 128 + fr;
  const int c0 = bcol + wc * 64 + kq * 4;
#pragma unroll
  for (int m = 0; m < 8; ++m)
#pragma unroll
    for (int n = 0; n < 4; ++n)
      *(f32x4*)(C + (r0 + m * 16) * NO + c0 + n * 16) = acc[m][n];
}

// ---- fallback (round-3 verified): fused reg-staged 128^2 GEMM (f16) ----
__global__ __launch_bounds__(256) void gemm_fb(
    const float* __restrict__ Xf, const float* __restrict__ Wdf,
    const float* __restrict__ Wsf, float* __restrict__ C) {
  __shared__ _Float16 lsA[128 * 32];
  __shared__ _Float16 lsB[128 * 32];

  const int t = threadIdx.x;
  const int lane = t & 63;
  const int wid = t >> 6;
  const int wr = wid >> 1, wc = wid & 1;

  const int nwg = (NT / 128) * (NO / 128);  // 2048
  const int swz = (blockIdx.x & 7) * (nwg >> 3) + (blockIdx.x >> 3);
  const int nbn = NO / 128;
  const int bm = swz / nbn, bn = swz % nbn;
  const long brow = (long)bm * 128, bcol = (long)bn * 128;

  const int srow = t >> 2;
  const int scol = (t & 3) * 8;
  const float* X  = Xf + (brow + srow) * (long)NK + scol;
  const float* Wd = Wdf + (bcol + srow) * (long)NK + scol;
  const float* Ws = Wsf + (bcol + srow) * (long)NK + scol;
  _Float16* lA = lsA + t * 8;
  _Float16* lB = lsB + t * 8;

  const int fr = lane & 15;
  const int kg = (lane >> 4) * 8;
  const _Float16* pA = lsA + (wr * 64 + fr) * 32 + kg;
  const _Float16* pB = lsB + (wc * 64 + fr) * 32 + kg;

  f32x4 acc[4][4] = {};

  for (int k0 = 0; k0 < NK; k0 += 32) {
    f32x4 aL0 = *(const f32x4*)(X + k0),  aH0 = *(const f32x4*)(X + k0 + 4);
    f32x4 aL1 = *(const f32x4*)(X + k0 + 64 * NK), aH1 = *(const f32x4*)(X + k0 + 64 * NK + 4);
    f32x4 dL0 = *(const f32x4*)(Wd + k0), dH0 = *(const f32x4*)(Wd + k0 + 4);
    f32x4 sL0 = *(const f32x4*)(Ws + k0), sH0 = *(const f32x4*)(Ws + k0 + 4);
    f32x4 dL1 = *(const f32x4*)(Wd + k0 + 64 * NK), dH1 = *(const f32x4*)(Wd + k0 + 64 * NK + 4);
    f32x4 sL1 = *(const f32x4*)(Ws + k0 + 64 * NK), sH1 = *(const f32x4*)(Ws + k0 + 64 * NK + 4);
    __syncthreads();
    f16x8 va0, va1, vb0, vb1;
#pragma unroll
    for (int j = 0; j < 4; ++j) {
      va0[j] = (_Float16)aL0[j];            va0[j + 4] = (_Float16)aH0[j];
      va1[j] = (_Float16)aL1[j];            va1[j + 4] = (_Float16)aH1[j];
      vb0[j] = (_Float16)(dL0[j] + sL0[j]); vb0[j + 4] = (_Float16)(dH0[j] + sH0[j]);
      vb1[j] = (_Float16)(dL1[j] + sL1[j]); vb1[j + 4] = (_Float16)(dH1[j] + sH1[j]);
    }
    *(f16x8*)lA = va0;
    *(f16x8*)(lA + 64 * 32) = va1;
    *(f16x8*)lB = vb0;
    *(f16x8*)(lB + 64 * 32) = vb1;
    __syncthreads();
    f16x8 af[4], bf[4];
#pragma unroll
    for (int i2 = 0; i2 < 4; ++i2) af[i2] = *(const f16x8*)(pA + i2 * 16 * 32);
#pragma unroll
    for (int i2 = 0; i2 < 4; ++i2) bf[i2] = *(const f16x8*)(pB + i2 * 16 * 32);
#pragma unroll
    for (int i2 = 0; i2 < 4; ++i2)
#pragma unroll
      for (int j2 = 0; j2 < 4; ++j2)
        acc[i2][j2] = __builtin_amdgcn_mfma_f32_16x16x32_f16(af[i2], bf[j2], acc[i2][j2], 0, 0, 0);
  }

  const int fq = lane >> 4;
#pragma unroll
  for (int i2 = 0; i2 < 4; ++i2)
#pragma unroll
    for (int j2 = 0; j2 < 4; ++j2)
#pragma unroll
      for (int r = 0; r < 4; ++r) {
        long row = brow + wr * 64 + i2 * 16 + fq * 4 + r;
        long col = bcol + wc * 64 + j2 * 16 + fr;
        C[row * NO + col] = acc[i2][j2][r];
      }
}

extern "C" void kernel_launch(void* const* d_in, const int* in_sizes, int n_in,
                              void* d_out, int out_size, void* d_ws, size_t ws_size,
                              hipStream_t stream) {
  const float* x   = (const float*)d_in[0];
  const float* wd  = (const float*)d_in[1];
  const float* wsp = (const float*)d_in[2];
  float* out = (float*)d_out;

  const size_t xh_bytes = (size_t)NT * NK * 2;  // 64 MiB
  const size_t wh_bytes = (size_t)NO * NK * 2;  // 32 MiB

  if (d_ws != nullptr && ws_size >= xh_bytes + wh_bytes) {
    short* xh = (short*)d_ws;
    short* wh = (short*)((char*)d_ws + xh_bytes);
    const int nx8 = NT * NK / 8;  // 4,194,304
    const int nw8 = NO * NK / 8;  // 2,097,152
    cvt_all<<<(nx8 + nw8) / 256, 256, 0, stream>>>(x, wd, wsp, xh, wh, nx8, nw8);
    gemm8p<<<(NT / 256) * (NO / 256), 512, 0, stream>>>(xh, wh, out);
  } else {
    gemm_fb<<<(NT / 128) * (NO / 128), 256, 0, stream>>>(x, wd, wsp, out);
  }
}

// Round 15
// 282.523 us; speedup vs baseline: 2.5986x; 2.5986x over previous
//
#include <hip/hip_runtime.h>
#include <stdint.h>

// out[8192,4096] = x @ (Wd + Ws)^T, fp32 device buffers (harness upcasts fp16).
// Wd,Ws elementwise complementary -> W = Wd+Ws exact, fp16-representable.
// Path A (ws >= 96MB): fused cvt -> bf16 in ws, then 256^2 MFMA GEMM
//   (r5/r11-verified schedule: single-barrier 8 phases, counted vmcnt(6),
//    st_16x32 swizzle, swapped-operand f32x4 NONTEMPORAL stores).
//   Best-measured config of the session (r11: 243.0 us gemm / 285.9 total).
// Path B: round-3-verified fused reg-staged GEMM (fallback, f16).

#define NT 8192
#define NO 4096
#define NK 4096

typedef float f32x4 __attribute__((ext_vector_type(4)));
typedef _Float16 f16x8 __attribute__((ext_vector_type(8)));
typedef __bf16 bf16x8 __attribute__((ext_vector_type(8)));
typedef short short8 __attribute__((ext_vector_type(8)));

__device__ __forceinline__ void gload_lds16(const void* g, void* l) {
  __builtin_amdgcn_global_load_lds(
      (const __attribute__((address_space(1))) void*)g,
      (__attribute__((address_space(3))) void*)l, 16, 0, 0);
}

#define BAR() __builtin_amdgcn_s_barrier()
#define WV6() asm volatile("s_waitcnt vmcnt(6)" ::: "memory")
#define PRIO1() __builtin_amdgcn_s_setprio(1)
#define PRIO0() __builtin_amdgcn_s_setprio(0)

__device__ __forceinline__ short f32_bf16(float f) {
  uint32_t u = __float_as_uint(f);
  u += 0x7FFFu + ((u >> 16) & 1u);  // RNE
  return (short)(u >> 16);
}

// ---- pre-pass: fp32 -> bf16, x and W=Wd+Ws in one launch ----
__global__ __launch_bounds__(256) void cvt_all(
    const float* __restrict__ x, const float* __restrict__ wd,
    const float* __restrict__ ws, short* __restrict__ xh,
    short* __restrict__ wh, int nx8, int nw8) {
  int i = blockIdx.x * 256 + threadIdx.x;
  if (i < nx8) {
    const f32x4* p = (const f32x4*)x + 2 * (size_t)i;
    f32x4 lo = p[0], hi = p[1];
    short8 r;
#pragma unroll
    for (int j = 0; j < 4; ++j) { r[j] = f32_bf16(lo[j]); r[j + 4] = f32_bf16(hi[j]); }
    *((short8*)xh + i) = r;
  } else {
    int j8 = i - nx8;
    if (j8 < nw8) {
      const f32x4* pd = (const f32x4*)wd + 2 * (size_t)j8;
      const f32x4* ps = (const f32x4*)ws + 2 * (size_t)j8;
      f32x4 dl = pd[0], dh = pd[1], sl = ps[0], sh = ps[1];
      short8 r;
#pragma unroll
      for (int j = 0; j < 4; ++j) {
        r[j] = f32_bf16(dl[j] + sl[j]);      // add exact: one addend is +/-0
        r[j + 4] = f32_bf16(dh[j] + sh[j]);
      }
      *((short8*)wh + j8) = r;
    }
  }
}

// ---- 256^2 GEMM, single-barrier 8 phases, 16x16x32 bf16 MFMA (r11) ----
// Tile 256x256, BK=64, 8 waves (2Mx4N), per-wave out 128x64.
// LDS [buf][op][half][16KB] = 128KB, st_16x32 swizzle (verified 0-conflict).
// Staging: linear global_load_lds dest + inverse-swizzled global source.

#define RDA(B_, MG) do { _Pragma("unroll") \
  for (int mm = 0; mm < 4; ++mm) { \
    ar[0][mm] = *(const short8*)(Ab[B_] + ((MG)*8 + mm*2 + 0) * 1024 + finner); \
    ar[1][mm] = *(const short8*)(Ab[B_] + ((MG)*8 + mm*2 + 1) * 1024 + finner); \
  } } while (0)

#define RDB(B_, NG) do { _Pragma("unroll") \
  for (int nn = 0; nn < 2; ++nn) { \
    br[0][(NG)*2+nn] = *(const short8*)(Bb[B_] + ((bsub + (NG)*2 + nn)*2 + 0) * 1024 + finner); \
    br[1][(NG)*2+nn] = *(const short8*)(Bb[B_] + ((bsub + (NG)*2 + nn)*2 + 1) * 1024 + finner); \
  } } while (0)

// swapped operands: D-row dim = W(N), D-col dim = X(M) -> contiguous-N acc
#define MM(MG, NG) do { _Pragma("unroll") \
  for (int ks = 0; ks < 2; ++ks) \
    _Pragma("unroll") for (int mm = 0; mm < 4; ++mm) \
      _Pragma("unroll") for (int nn = 0; nn < 2; ++nn) \
        acc[(MG)*4+mm][(NG)*2+nn] = __builtin_amdgcn_mfma_f32_16x16x32_bf16( \
            __builtin_bit_cast(bf16x8, br[ks][(NG)*2+nn]), \
            __builtin_bit_cast(bf16x8, ar[ks][mm]), \
            acc[(MG)*4+mm][(NG)*2+nn], 0, 0, 0); \
  } while (0)

#define STG(BUF_, OP_, H_, S_, KCOL) \
  gload_lds16(((OP_) ? Wrow : Xrow) + ((H_)*128 + (S_)*64) * NK + (KCOL), \
              ldsc + (BUF_)*65536 + (OP_)*32768 + (H_)*16384 + (S_)*8192 + t16)

__global__ __launch_bounds__(512, 2) void gemm8p(
    const short* __restrict__ Xg, const short* __restrict__ Wg,
    float* __restrict__ C) {
  __shared__ short lds[2][2][2][8192];  // [buf][op][half][16KB] = 128 KiB
  char* ldsc = (char*)&lds[0][0][0][0];

  const int t = threadIdx.x;      // 0..511
  const int lane = t & 63;
  const int wv = t >> 6;          // 0..7
  const int wr = wv >> 2;         // 0..1  (M half)
  const int wc = wv & 3;          // 0..3  (N quarter)
  const int fr = lane & 15;
  const int kq = lane >> 4;       // 0..3
  const int t16 = t * 16;

  // XCD-aware bijective swizzle (nwg = 512 = 8*64)
  const int swz = (blockIdx.x & 7) * 64 + (blockIdx.x >> 3);
  const int bm = swz >> 4, bn = swz & 15;   // 32 x 16 tiles
  const int brow = bm * 256, bcol = bn * 256;

  // staging: invert st_16x32 swizzle on the global source (r5-r12 verified)
  const int o = t16;
  const int sub = o >> 10;
  const int inner = o & 1023;
  const int innsw = inner ^ (((inner >> 9) & 1) << 5);
  const int rloc = ((sub >> 1) << 4) | ((innsw >> 6) & 15);  // 0..63
  const int kloc = ((sub & 1) << 5) | ((innsw >> 1) & 31);   // 0..63 (8-granular)

  const short* Xrow = Xg + (brow + rloc) * NK + kloc;
  const short* Wrow = Wg + (bcol + rloc) * NK + kloc;

  // fragment read offset: row fr (16-row subtile), k-group kq*8 halves
  const int finner = ((fr << 6) | (kq << 4)) ^ ((fr & 8) << 2);
  const char* Ab[2] = { ldsc + wr * 16384, ldsc + 65536 + wr * 16384 };
  const char* Bb[2] = { ldsc + 32768 + (wc >> 1) * 16384,
                        ldsc + 65536 + 32768 + (wc >> 1) * 16384 };
  const int bsub = (wc & 1) * 4;

  short8 ar[2][4], br[2][4];
  f32x4 acc[8][4] = {};

  // ---- prologue: tile0 (8 gloads -> buf0), tile1 first 6 -> buf1 ----
  STG(0, 0, 0, 0, 0); STG(0, 0, 0, 1, 0); STG(0, 0, 1, 0, 0); STG(0, 0, 1, 1, 0);
  STG(0, 1, 0, 0, 0); STG(0, 1, 0, 1, 0); STG(0, 1, 1, 0, 0); STG(0, 1, 1, 1, 0);
  STG(1, 0, 0, 0, 64); STG(1, 0, 1, 0, 64);
  STG(1, 1, 0, 0, 64); STG(1, 1, 0, 1, 64); STG(1, 1, 1, 0, 64); STG(1, 1, 1, 1, 64);
  WV6(); BAR();

#pragma unroll 1
  for (int i = 0; i < NK / 128; ++i) {
    const int k1 = i * 128 + 64;
    const int kt2 = (i * 128 + 128) & (NK - 1);  // tile t+2 (wraps harmlessly)
    const int kt3 = (i * 128 + 192) & (NK - 1);  // tile t+3

    // P0: compute buf0 (m0-3 x n0-1); stage t1.A s1 -> buf1
    RDA(0, 0); RDB(0, 0);
    STG(1, 0, 0, 1, k1); STG(1, 0, 1, 1, k1);
    PRIO1(); MM(0, 0); PRIO0(); BAR();
    // P1: (m0-3 x n2-3); stage t2.A s0 -> buf0
    RDB(0, 1);
    STG(0, 0, 0, 0, kt2); STG(0, 0, 1, 0, kt2);
    PRIO1(); MM(0, 1); PRIO0(); BAR();
    // P2: (m4-7 x n0-1); stage t2.B half0 -> buf0
    RDA(0, 1);
    STG(0, 1, 0, 0, kt2); STG(0, 1, 0, 1, kt2);
    PRIO1(); MM(1, 0); PRIO0(); BAR();
    // P3: (m4-7 x n2-3); stage t2.B half1; counted vmcnt after MFMA
    STG(0, 1, 1, 0, kt2); STG(0, 1, 1, 1, kt2);
    PRIO1(); MM(1, 1); PRIO0();
    WV6(); BAR();
    // P4: compute buf1 (m0-3 x n0-1); stage t2.A s1 -> buf0
    RDA(1, 0); RDB(1, 0);
    STG(0, 0, 0, 1, kt2); STG(0, 0, 1, 1, kt2);
    PRIO1(); MM(0, 0); PRIO0(); BAR();
    // P5: (m0-3 x n2-3); stage t3.A s0 -> buf1
    RDB(1, 1);
    STG(1, 0, 0, 0, kt3); STG(1, 0, 1, 0, kt3);
    PRIO1(); MM(0, 1); PRIO0(); BAR();
    // P6: (m4-7 x n0-1); stage t3.B half0 -> buf1
    RDA(1, 1);
    STG(1, 1, 0, 0, kt3); STG(1, 1, 0, 1, kt3);
    PRIO1(); MM(1, 0); PRIO0(); BAR();
    // P7: (m4-7 x n2-3); stage t3.B half1; counted vmcnt after MFMA
    STG(1, 1, 1, 0, kt3); STG(1, 1, 1, 1, kt3);
    PRIO1(); MM(1, 1); PRIO0();
    WV6(); BAR();
  }

  // Swapped-operand C/D layout: lane's 4 acc elems are CONTIGUOUS in N.
  // row = brow + wr*128 + m*16 + fr ; col = bcol + wc*64 + n*16 + kq*4 + [0,4)
  // C is write-once/never-read -> nontemporal keeps L2/L3 for X/W reuse.
  const long r0 = brow + wr * 128 + fr;
  const int c0 = bcol + wc * 64 + kq * 4;
#pragma unroll
  for (int m = 0; m < 8; ++m)
#pragma unroll
    for (int n = 0; n < 4; ++n)
      __builtin_nontemporal_store(
          acc[m][n], (f32x4*)(C + (r0 + m * 16) * NO + c0 + n * 16));
}

// ---- fallback (round-3 verified): fused reg-staged 128^2 GEMM (f16) ----
__global__ __launch_bounds__(256) void gemm_fb(
    const float* __restrict__ Xf, const float* __restrict__ Wdf,
    const float* __restrict__ Wsf, float* __restrict__ C) {
  __shared__ _Float16 lsA[128 * 32];
  __shared__ _Float16 lsB[128 * 32];

  const int t = threadIdx.x;
  const int lane = t & 63;
  const int wid = t >> 6;
  const int wr = wid >> 1, wc = wid & 1;

  const int nwg = (NT / 128) * (NO / 128);  // 2048
  const int swz = (blockIdx.x & 7) * (nwg >> 3) + (blockIdx.x >> 3);
  const int nbn = NO / 128;
  const int bm = swz / nbn, bn = swz % nbn;
  const long brow = (long)bm * 128, bcol = (long)bn * 128;

  const int srow = t >> 2;
  const int scol = (t & 3) * 8;
  const float* X  = Xf + (brow + srow) * (long)NK + scol;
  const float* Wd = Wdf + (bcol + srow) * (long)NK + scol;
  const float* Ws = Wsf + (bcol + srow) * (long)NK + scol;
  _Float16* lA = lsA + t * 8;
  _Float16* lB = lsB + t * 8;

  const int fr = lane & 15;
  const int kg = (lane >> 4) * 8;
  const _Float16* pA = lsA + (wr * 64 + fr) * 32 + kg;
  const _Float16* pB = lsB + (wc * 64 + fr) * 32 + kg;

  f32x4 acc[4][4] = {};

  for (int k0 = 0; k0 < NK; k0 += 32) {
    f32x4 aL0 = *(const f32x4*)(X + k0),  aH0 = *(const f32x4*)(X + k0 + 4);
    f32x4 aL1 = *(const f32x4*)(X + k0 + 64 * NK), aH1 = *(const f32x4*)(X + k0 + 64 * NK + 4);
    f32x4 dL0 = *(const f32x4*)(Wd + k0), dH0 = *(const f32x4*)(Wd + k0 + 4);
    f32x4 sL0 = *(const f32x4*)(Ws + k0), sH0 = *(const f32x4*)(Ws + k0 + 4);
    f32x4 dL1 = *(const f32x4*)(Wd + k0 + 64 * NK), dH1 = *(const f32x4*)(Wd + k0 + 64 * NK + 4);
    f32x4 sL1 = *(const f32x4*)(Ws + k0 + 64 * NK), sH1 = *(const f32x4*)(Ws + k0 + 64 * NK + 4);
    __syncthreads();
    f16x8 va0, va1, vb0, vb1;
#pragma unroll
    for (int j = 0; j < 4; ++j) {
      va0[j] = (_Float16)aL0[j];            va0[j + 4] = (_Float16)aH0[j];
      va1[j] = (_Float16)aL1[j];            va1[j + 4] = (_Float16)aH1[j];
      vb0[j] = (_Float16)(dL0[j] + sL0[j]); vb0[j + 4] = (_Float16)(dH0[j] + sH0[j]);
      vb1[j] = (_Float16)(dL1[j] + sL1[j]); vb1[j + 4] = (_Float16)(dH1[j] + sH1[j]);
    }
    *(f16x8*)lA = va0;
    *(f16x8*)(lA + 64 * 32) = va1;
    *(f16x8*)lB = vb0;
    *(f16x8*)(lB + 64 * 32) = vb1;
    __syncthreads();
    f16x8 af[4], bf[4];
#pragma unroll
    for (int i2 = 0; i2 < 4; ++i2) af[i2] = *(const f16x8*)(pA + i2 * 16 * 32);
#pragma unroll
    for (int i2 = 0; i2 < 4; ++i2) bf[i2] = *(const f16x8*)(pB + i2 * 16 * 32);
#pragma unroll
    for (int i2 = 0; i2 < 4; ++i2)
#pragma unroll
      for (int j2 = 0; j2 < 4; ++j2)
        acc[i2][j2] = __builtin_amdgcn_mfma_f32_16x16x32_f16(af[i2], bf[j2], acc[i2][j2], 0, 0, 0);
  }

  const int fq = lane >> 4;
#pragma unroll
  for (int i2 = 0; i2 < 4; ++i2)
#pragma unroll
    for (int j2 = 0; j2 < 4; ++j2)
#pragma unroll
      for (int r = 0; r < 4; ++r) {
        long row = brow + wr * 64 + i2 * 16 + fq * 4 + r;
        long col = bcol + wc * 64 + j2 * 16 + fr;
        C[row * NO + col] = acc[i2][j2][r];
      }
}

extern "C" void kernel_launch(void* const* d_in, const int* in_sizes, int n_in,
                              void* d_out, int out_size, void* d_ws, size_t ws_size,
                              hipStream_t stream) {
  const float* x   = (const float*)d_in[0];
  const float* wd  = (const float*)d_in[1];
  const float* wsp = (const float*)d_in[2];
  float* out = (float*)d_out;

  const size_t xh_bytes = (size_t)NT * NK * 2;  // 64 MiB
  const size_t wh_bytes = (size_t)NO * NK * 2;  // 32 MiB

  if (d_ws != nullptr && ws_size >= xh_bytes + wh_bytes) {
    short* xh = (short*)d_ws;
    short* wh = (short*)((char*)d_ws + xh_bytes);
    const int nx8 = NT * NK / 8;  // 4,194,304
    const int nw8 = NO * NK / 8;  // 2,097,152
    cvt_all<<<(nx8 + nw8) / 256, 256, 0, stream>>>(x, wd, wsp, xh, wh, nx8, nw8);
    gemm8p<<<(NT / 256) * (NO / 256), 512, 0, stream>>>(xh, wh, out);
  } else {
    gemm_fb<<<(NT / 128) * (NO / 128), 256, 0, stream>>>(x, wd, wsp, out);
  }
}